// Round 10
// baseline (195.598 us; speedup 1.0000x reference)
//
#include <hip/hip_runtime.h>

typedef unsigned short u16;
typedef unsigned int   u32;

using short8 = __attribute__((ext_vector_type(8))) short;
using f32x4  = __attribute__((ext_vector_type(4))) float;
using half4  = __attribute__((ext_vector_type(4))) _Float16;
using half8  = __attribute__((ext_vector_type(8))) _Float16;

// SCALE * log2(e) folded into q at the QKV epilogue
#define QSCALE 0.18033688011112042f

__device__ __forceinline__ u16 f2bf(float f) {
  u32 u = __float_as_uint(f);
  return (u16)((u + 0x8000u) >> 16);
}
__device__ __forceinline__ u16 f2h(float f) {
  _Float16 h = (_Float16)f;
  return __builtin_bit_cast(u16, h);
}

// async global->LDS DMA, 16B per lane; lds dest = wave-uniform base + lane*16
__device__ __forceinline__ void gld16(const u16* g, u16* l) {
  __builtin_amdgcn_global_load_lds(
      (const __attribute__((address_space(1))) unsigned int*)g,
      (__attribute__((address_space(3))) unsigned int*)l, 16, 0, 0);
}

// ---------------- x fp32 -> bf16, 4 elems/thread ----------------
__global__ __launch_bounds__(256) void cvt_x(const float* __restrict__ in,
                                             u16* __restrict__ out) {
  int idx = blockIdx.x * 256 + threadIdx.x;
  float4 v = reinterpret_cast<const float4*>(in)[idx];
  ushort4 o;
  o.x = f2bf(v.x); o.y = f2bf(v.y); o.z = f2bf(v.z); o.w = f2bf(v.w);
  reinterpret_cast<ushort4*>(out)[idx] = o;
}

// ---------------- fp32 [R][C] -> bf16 [C][R] (B^T layout for GEMM) ----------------
__global__ __launch_bounds__(256) void transpose_w(const float* __restrict__ in,
                                                   u16* __restrict__ out,
                                                   int R, int C) {
  __shared__ u32 s[32][33];
  int c0 = blockIdx.x * 32, r0 = blockIdx.y * 32;
  int j = threadIdx.x & 31, i0 = threadIdx.x >> 5;
#pragma unroll
  for (int p = 0; p < 4; ++p) {
    int i = i0 + p * 8;
    s[i][j] = f2bf(in[(size_t)(r0 + i) * C + c0 + j]);
  }
  __syncthreads();
#pragma unroll
  for (int p = 0; p < 4; ++p) {
    int jj = i0 + p * 8;
    out[(size_t)(c0 + jj) * R + r0 + j] = (u16)s[j][jj];
  }
}

// ---------------- 4-resident bf16 GEMM: BM=64 x BN=NI*32, BK=32 -------------
// Session-wide finding: every kernel at 2-3 waves/SIMD runs at 2.5-3x its
// issue demand; 4 waves/SIMD packs ~1.5x. Both prior GEMM structures (m97
// 3/CU, pipelined 2/CU) tied at ~45-50us vs a 12.4us MFMA floor. This shape
// targets residency: 4-wave blocks (2x2, wave = 32 x NI*16, acc[2][NI]),
// small dbuf LDS (2 x (4+NI*2) KB), grid = exactly 4 blocks/CU, stage-ahead
// {issue next-tile gld16 -> compute -> sync}. Swizzle identical to the
// verified gemm_bt (chunk c of row r stores global chunk c^(r&3); frag read
// chunk = quad^(r&3)). EPI==0: QKV scatter epilogue (verified). EPI==1: fp32.
template <int EPI, int NI>
__global__ __launch_bounds__(256, 4) void gemm4(
    const u16* __restrict__ A, const u16* __restrict__ Bt,
    const float* __restrict__ bias, float* __restrict__ c_out,
    u16* __restrict__ q_out, u16* __restrict__ k_out, u16* __restrict__ vt_out,
    int N, int K) {
  constexpr int BN = NI * 32;
  constexpr int PB = BN / 64;  // B staging chunks per thread
  __shared__ __align__(16) u16 As[2][64 * 32];
  __shared__ __align__(16) u16 Bs[2][BN * 32];
  const int tid = threadIdx.x;
  const int lane = tid & 63, wv = tid >> 6;
  const int l16 = lane & 15, quad = lane >> 4;
  const int wm = wv & 1, wn = wv >> 1;
  const int bx = blockIdx.x, by = blockIdx.y;

  const u16* Ab = A + (size_t)by * 64 * K;
  const u16* Bb = Bt + (size_t)bx * BN * K;

  // staging source pointers, swizzle folded once; advance += 32 per K-step
  const u16* sA = Ab + (size_t)(tid >> 2) * K + (((tid & 3) ^ ((tid >> 2) & 3)) << 3);
  const int dA = tid << 3;
  const u16* sB[PB];
  int dB[PB];
#pragma unroll
  for (int p = 0; p < PB; ++p) {
    int id = p * 256 + tid;
    sB[p] = Bb + (size_t)(id >> 2) * K + (((id & 3) ^ ((id >> 2) & 3)) << 3);
    dB[p] = id << 3;
  }

  // tile-invariant LDS read offsets
  int aoff[2], boff[NI];
#pragma unroll
  for (int mi = 0; mi < 2; ++mi) {
    int r = wm * 32 + mi * 16 + l16;
    aoff[mi] = r * 32 + ((quad ^ (r & 3)) << 3);
  }
#pragma unroll
  for (int ni = 0; ni < NI; ++ni) {
    int r = wn * (BN / 2) + ni * 16 + l16;
    boff[ni] = r * 32 + ((quad ^ (r & 3)) << 3);
  }

  const f32x4 fzero = {0.0f, 0.0f, 0.0f, 0.0f};
  f32x4 acc[2][NI];
#pragma unroll
  for (int i = 0; i < 2; ++i)
#pragma unroll
    for (int j = 0; j < NI; ++j) acc[i][j] = fzero;

#define STAGE4(T)                                            \
  do {                                                       \
    gld16(sA, &As[T][dA]);                                   \
    sA += 32;                                                \
    _Pragma("unroll")                                        \
    for (int p = 0; p < PB; ++p) {                           \
      gld16(sB[p], &Bs[T][dB[p]]);                           \
      sB[p] += 32;                                           \
    }                                                        \
  } while (0)

#define KSTEP4(S)                                                          \
  do {                                                                     \
    short8 a0 = *reinterpret_cast<const short8*>(&As[S][aoff[0]]);         \
    short8 a1 = *reinterpret_cast<const short8*>(&As[S][aoff[1]]);         \
    short8 bb[NI];                                                         \
    _Pragma("unroll")                                                      \
    for (int j = 0; j < NI; ++j)                                           \
      bb[j] = *reinterpret_cast<const short8*>(&Bs[S][boff[j]]);           \
    __builtin_amdgcn_s_setprio(1);                                         \
    _Pragma("unroll")                                                      \
    for (int j = 0; j < NI; ++j) {                                         \
      acc[0][j] = __builtin_amdgcn_mfma_f32_16x16x32_bf16(a0, bb[j], acc[0][j], 0, 0, 0); \
      acc[1][j] = __builtin_amdgcn_mfma_f32_16x16x32_bf16(a1, bb[j], acc[1][j], 0, 0, 0); \
    }                                                                      \
    __builtin_amdgcn_s_setprio(0);                                         \
  } while (0)

  // prologue: stage K-step 0
  STAGE4(0);
  __syncthreads();

  const int NK = K / 32;  // 32 steps
  for (int ks = 0; ks < NK; ks += 2) {
    if (ks + 1 < NK) STAGE4(1);  // issue next step's loads, compute under them
    KSTEP4(0);
    __syncthreads();
    if (ks + 2 < NK) STAGE4(0);
    KSTEP4(1);
    __syncthreads();
  }
#undef STAGE4
#undef KSTEP4

  // epilogue
#pragma unroll
  for (int mi = 0; mi < 2; ++mi)
#pragma unroll
    for (int ni = 0; ni < NI; ++ni) {
      int col = bx * BN + wn * (BN / 2) + ni * 16 + l16;
      float bv = bias[col];
      int row0 = by * 64 + wm * 32 + mi * 16 + quad * 4;
      if (EPI == 1) {
#pragma unroll
        for (int r = 0; r < 4; ++r)
          c_out[(size_t)(row0 + r) * N + col] = acc[mi][ni][r] + bv;
      } else {
        int which = col >> 10, rem = col & 1023;
        int h = rem >> 6, d = rem & 63;
        int b = row0 >> 11, sq0 = row0 & 2047;
        int bh = (b << 4) + h;
        if (which == 2) {
          // V fp16 frag layout: 4 consecutive t -> one 8B store
          ushort4 pk;
          pk.x = f2h(acc[mi][ni][0] + bv);
          pk.y = f2h(acc[mi][ni][1] + bv);
          pk.z = f2h(acc[mi][ni][2] + bv);
          pk.w = f2h(acc[mi][ni][3] + bv);
          size_t off = (size_t)bh * 131072 +
                       (((sq0 >> 2) * 16 + (d & 15)) * 16 + ((d >> 4) << 2));
          *reinterpret_cast<ushort4*>(&vt_out[off]) = pk;
        } else {
          size_t base = (size_t)(bh * 2048 + sq0) * 64 + d;
#pragma unroll
          for (int r = 0; r < 4; ++r) {
            float val = acc[mi][ni][r] + bv;
            if (which == 0) q_out[base + r * 64] = f2bf(val * QSCALE);
            else            k_out[base + r * 64] = f2bf(val);
          }
        }
      }
    }
}

// ---------------- flash attention (r7 version: best measured, 51.2 us) ------
// 64 Q rows/block, 4 waves (16 q each), 2-buf LDS K/V, hoisted addressing,
// setprio around MFMA clusters, grid (32,32) = 4 blocks/CU = 4 waves/SIMD.
__global__ __launch_bounds__(256, 4) void attn(
    const u16* __restrict__ q_buf, const u16* __restrict__ k_buf,
    const u16* __restrict__ vt_buf, u16* __restrict__ o_buf) {
  __shared__ __align__(16) u16 Ks[2][4096];
  __shared__ __align__(16) u16 Vs[2][4096];

  const int tid = threadIdx.x;
  const int lane = tid & 63, w = tid >> 6;
  const int l16 = lane & 15, quad = lane >> 4;
  const int bh = blockIdx.x, q0 = blockIdx.y * 64;

  const u16* qg = q_buf + (size_t)bh * 131072 + (q0 + w * 16) * 64;
  const u16* kg = k_buf + (size_t)bh * 131072;
  const u16* vg = vt_buf + (size_t)bh * 131072;

  short8 qb[2];
#pragma unroll
  for (int kk = 0; kk < 2; ++kk)
    qb[kk] = *reinterpret_cast<const short8*>(qg + l16 * 64 + kk * 32 + quad * 8);

  const int idA = tid, idB = 256 + tid;
  const u16* ksA = kg + (idA >> 3) * 64 + (((idA & 7) ^ ((idA >> 3) & 7)) << 3);
  const u16* ksB = kg + (idB >> 3) * 64 + (((idB & 7) ^ ((idB >> 3) & 7)) << 3);
  const u16* vsA = vg + ((idA ^ ((idA >> 4) & 1)) << 3);
  const u16* vsB = vg + ((idB ^ ((idB >> 4) & 1)) << 3);
  const int ldA = idA << 3, ldB = idB << 3;

  int k0o[4], k1o[4], v0o[4], v1o[4];
#pragma unroll
  for (int t = 0; t < 4; ++t) {
    int rr = t * 16 + l16;
    k0o[t] = rr * 64 + ((quad ^ (rr & 7)) << 3);
    k1o[t] = rr * 64 + (((4 + quad) ^ (rr & 7)) << 3);
    int gb = (t * 4 + quad) * 32 + l16 * 2;
    int sw = (l16 >> 3) & 1;
    v0o[t] = (gb + sw) << 3;
    v1o[t] = (gb + (sw ^ 1)) << 3;
  }

  const f32x4 fzero = {0.0f, 0.0f, 0.0f, 0.0f};
  f32x4 o_acc[4];
  float l_acc = 0.f;
#pragma unroll
  for (int nd = 0; nd < 4; ++nd) o_acc[nd] = fzero;

#define STAGE(BUF)                           \
  do {                                       \
    gld16(ksA, &Ks[BUF][ldA]);               \
    gld16(ksB, &Ks[BUF][ldB]);               \
    gld16(vsA, &Vs[BUF][ldA]);               \
    gld16(vsB, &Vs[BUF][ldB]);               \
    ksA += 4096; ksB += 4096;                \
    vsA += 4096; vsB += 4096;                \
  } while (0)

#define TILE(BUF)                                                         \
  do {                                                                    \
    _Pragma("unroll")                                                     \
    for (int t = 0; t < 4; ++t) {                                         \
      short8 k0f = *reinterpret_cast<const short8*>(&Ks[BUF][k0o[t]]);    \
      short8 k1f = *reinterpret_cast<const short8*>(&Ks[BUF][k1o[t]]);    \
      half8 v0 = *reinterpret_cast<const half8*>(&Vs[BUF][v0o[t]]);       \
      half8 v1 = *reinterpret_cast<const half8*>(&Vs[BUF][v1o[t]]);       \
      half4 vb0 = __builtin_shufflevector(v0, v0, 0, 1, 2, 3);            \
      half4 vb1 = __builtin_shufflevector(v0, v0, 4, 5, 6, 7);            \
      half4 vb2 = __builtin_shufflevector(v1, v1, 0, 1, 2, 3);            \
      half4 vb3 = __builtin_shufflevector(v1, v1, 4, 5, 6, 7);            \
      __builtin_amdgcn_s_setprio(1);                                      \
      f32x4 s = __builtin_amdgcn_mfma_f32_16x16x32_bf16(k0f, qb[0], fzero, 0, 0, 0); \
      s = __builtin_amdgcn_mfma_f32_16x16x32_bf16(k1f, qb[1], s, 0, 0, 0);\
      __builtin_amdgcn_s_setprio(0);                                      \
      float p0 = __builtin_amdgcn_exp2f(s[0]);                            \
      float p1 = __builtin_amdgcn_exp2f(s[1]);                            \
      float p2 = __builtin_amdgcn_exp2f(s[2]);                            \
      float p3 = __builtin_amdgcn_exp2f(s[3]);                            \
      l_acc += (p0 + p1) + (p2 + p3);                                     \
      half4 pa;                                                           \
      pa[0] = (_Float16)p0; pa[1] = (_Float16)p1;                         \
      pa[2] = (_Float16)p2; pa[3] = (_Float16)p3;                         \
      __builtin_amdgcn_s_setprio(1);                                      \
      o_acc[0] = __builtin_amdgcn_mfma_f32_16x16x16f16(pa, vb0, o_acc[0], 0, 0, 0); \
      o_acc[1] = __builtin_amdgcn_mfma_f32_16x16x16f16(pa, vb1, o_acc[1], 0, 0, 0); \
      o_acc[2] = __builtin_amdgcn_mfma_f32_16x16x16f16(pa, vb2, o_acc[2], 0, 0, 0); \
      o_acc[3] = __builtin_amdgcn_mfma_f32_16x16x16f16(pa, vb3, o_acc[3], 0, 0, 0); \
      __builtin_amdgcn_s_setprio(0);                                      \
    }                                                                     \
  } while (0)

  STAGE(0);
  __syncthreads();

  for (int i = 0; i < 32; i += 2) {
    if (i + 1 < 32) STAGE(1);
    TILE(0);
    __syncthreads();
    if (i + 2 < 32) STAGE(0);
    TILE(1);
    __syncthreads();
  }
#undef STAGE
#undef TILE

  l_acc += __shfl_xor(l_acc, 16, 64);
  l_acc += __shfl_xor(l_acc, 32, 64);

  const int b = bh >> 4, h = bh & 15;
  float lv[4];
#pragma unroll
  for (int r = 0; r < 4; ++r)
    lv[r] = __shfl(l_acc, quad * 4 + r, 64);
#pragma unroll
  for (int nd = 0; nd < 4; ++nd) {
#pragma unroll
    for (int r = 0; r < 4; ++r) {
      int sq = q0 + w * 16 + quad * 4 + r;
      o_buf[(size_t)(b * 2048 + sq) * 1024 + h * 64 + nd * 16 + l16] =
          f2bf(o_acc[nd][r] / lv[r]);
    }
  }
}

extern "C" void kernel_launch(void* const* d_in, const int* in_sizes, int n_in,
                              void* d_out, int out_size, void* d_ws, size_t ws_size,
                              hipStream_t stream) {
  (void)in_sizes; (void)n_in; (void)out_size; (void)ws_size;
  const float* x     = (const float*)d_in[0];
  const float* W_qkv = (const float*)d_in[1];
  const float* b_qkv = (const float*)d_in[2];
  const float* W_out = (const float*)d_in[3];
  const float* b_out = (const float*)d_in[4];
  float* out = (float*)d_out;

  // workspace layout (48 MB total)
  char* ws = (char*)d_ws;
  u16* x_bf   = (u16*)(ws);              //  8 MB  [4096][1024] bf16
  u16* wqkv_t = (u16*)(ws + 8388608);    //  6 MB  [3072][1024] bf16
  u16* wout_t = (u16*)(ws + 14680064);   //  2 MB  [1024][1024] bf16
  u16* q_buf  = (u16*)(ws + 16777216);   //  8 MB  [32][2048][64] bf16
  u16* k_buf  = (u16*)(ws + 25165824);   //  8 MB  [32][2048][64] bf16
  u16* vt_buf = (u16*)(ws + 33554432);   //  8 MB  [32] V-frag fp16 layout
  u16* o_bf   = (u16*)(ws + 41943040);   //  8 MB  [4096][1024] bf16

  cvt_x<<<4096, 256, 0, stream>>>(x, x_bf);
  transpose_w<<<dim3(96, 32), 256, 0, stream>>>(W_qkv, wqkv_t, 1024, 3072);
  transpose_w<<<dim3(32, 32), 256, 0, stream>>>(W_out, wout_t, 1024, 1024);
  // QKV: BM=64 x BN=192, grid (3072/192, 4096/64) = (16,64) = 1024 = 4/CU
  gemm4<0, 6><<<dim3(16, 64), 256, 0, stream>>>(x_bf, wqkv_t, b_qkv, nullptr,
                                                q_buf, k_buf, vt_buf, 3072, 1024);
  attn<<<dim3(32, 32), 256, 0, stream>>>(q_buf, k_buf, vt_buf, o_bf);
  // out-proj: BM=64 x BN=64, grid (1024/64, 4096/64) = (16,64) = 1024 = 4/CU
  gemm4<1, 2><<<dim3(16, 64), 256, 0, stream>>>(o_bf, wout_t, b_out, out,
                                                nullptr, nullptr, nullptr, 1024, 1024);
}